// Round 9
// baseline (610.504 us; speedup 1.0000x reference)
//
#include <hip/hip_runtime.h>
#include <hip/hip_bf16.h>
#include <hip/hip_fp16.h>
#include <math.h>
#include <stdint.h>

// GNN relation module, restructured:
//   h_e = P[src] + Q[dst]  (node-level GEMMs instead of edge-level)
// GEMMs: single-term bf16 MFMA. PQ stored fp16 (epilogue CLAMPED to fp16
// range — overflow-proof). edge_pass v8b: ALGEBRAIC DECOMPOSITION —
// per-edge work is only pk_max(P) and S[d] += P[src]:
//   max_e h = Q + max_e P;  Σh = Σ_d S[d] + Σ_n indeg·Q;
//   Σh² = Σ_n outdeg·P² + Σ_n indeg·Q² + 2·Σ_d Q[d]·S[d].
// (Round-8 bug: dense_terms also added Σ outdeg·P into Σh — double count
// with edge_pass's ΣS — corrupt BN stats → fp16 overflow → inf. Fixed.)
// finalize fused into normalize_write; one upfront memset zeroes
// counts+outdeg+stats. segment_max commutes with BN+ReLU (slope >= 0).
// Empty segments via counts==0.

constexpr int NNODE = 16384;
constexpr int NEDGE = 262144;
constexpr int CD    = 256;
constexpr float EPSB = 1e-5f;

typedef __attribute__((ext_vector_type(8))) short bf16x8;
typedef __attribute__((ext_vector_type(8))) unsigned short u16x8;
typedef __attribute__((ext_vector_type(4))) float f32x4;
typedef __attribute__((ext_vector_type(4))) _Float16 h16x4;
typedef __attribute__((ext_vector_type(8))) _Float16 h16x8;
typedef __attribute__((ext_vector_type(2))) _Float16 h16x2;

__device__ inline unsigned short bf_hi_rne(float f) {
  unsigned int u = __float_as_uint(f);
  u += 0x7fffu + ((u >> 16) & 1u);
  return (unsigned short)(u >> 16);
}

__device__ __forceinline__ void gload16(const void* g, void* l) {
  __builtin_amdgcn_global_load_lds(
      (__attribute__((address_space(1))) void*)(void*)g,
      (__attribute__((address_space(3))) void*)l, 16, 0, 0);
}

__device__ __forceinline__ _Float16 to_h16_sat(float f) {
  return (_Float16)fminf(fmaxf(f, -65504.0f), 65504.0f);
}

// ---------------- weight prep: transposed combined matrices, bf16 ----------------
__global__ void build_wt(const float* __restrict__ W, const float* __restrict__ b,
                         unsigned short* __restrict__ Wth, int has_box) {
  int k = threadIdx.x;          // 0..319
  int n = blockIdx.x;           // 0..511
  if (k >= 288) return;
  float v = 0.0f;
  if (n < 256) {                // P part
    if (k < 256)      v = W[k * 256 + n];
    else if (k < 263) v = has_box ? W[(512 + (k - 256)) * 256 + n] : 0.0f;
  } else {                      // Q part
    int n2 = n - 256;
    if (k < 256)      v = W[(256 + k) * 256 + n2] - W[k * 256 + n2];
    else if (k < 263) v = has_box ? -W[(512 + (k - 256)) * 256 + n2] : 0.0f;
    else if (k == 263) v = b[n2];
  }
  Wth[n * 288 + k] = bf_hi_rne(v);
}

__global__ void build_wtg(const float* __restrict__ Wg, const float* __restrict__ bg,
                          unsigned short* __restrict__ Wth) {
  int k = threadIdx.x;
  int n = blockIdx.x;
  if (k >= 288) return;
  float v = 0.0f;
  if (k < 263)       v = Wg[k * 256 + n];
  else if (k == 263) v = bg[n];
  Wth[n * 288 + k] = bf_hi_rne(v);
}

// box bf16, padded to 32 cols: {rois[0..6], 1.0, 0 x 24}
__global__ void build_boxf16(const float* __restrict__ rois,
                             unsigned short* __restrict__ hi) {
  int n = blockIdx.x * 256 + threadIdx.x;
  u16x8 h8 = (u16x8)0;
#pragma unroll
  for (int j = 0; j < 8; j++) {
    float v = (j < 7) ? rois[n * 7 + j] : 1.0f;
    h8[j] = bf_hi_rne(v);
  }
  *(u16x8*)(hi + (size_t)n * 32) = h8;
  u16x8 z = (u16x8)0;
#pragma unroll
  for (int c = 1; c < 4; c++) *(u16x8*)(hi + (size_t)n * 32 + c * 8) = z;
}

// fp32 -> bf16 (8 elems/thread)
__global__ void convert_split(const float* __restrict__ src,
                              unsigned short* __restrict__ hi) {
  size_t i0 = ((size_t)blockIdx.x * 256 + threadIdx.x) * 8;
  float4 a = *(const float4*)(src + i0);
  float4 b = *(const float4*)(src + i0 + 4);
  float v[8] = {a.x, a.y, a.z, a.w, b.x, b.y, b.z, b.w};
  u16x8 h8;
#pragma unroll
  for (int j = 0; j < 8; j++) h8[j] = bf_hi_rne(v[j]);
  *(u16x8*)(hi + i0) = h8;
}

// ---------------- CSR build (counting sort by dst) ----------------
__global__ void hist_kernel(const int* __restrict__ idx, int* __restrict__ counts) {
  int e = blockIdx.x * 256 + threadIdx.x;
  atomicAdd(&counts[idx[e]], 1);
}

__global__ __launch_bounds__(1024) void scan_kernel(const int* __restrict__ counts,
                                                    int* __restrict__ offsets,
                                                    int* __restrict__ cursor) {
  __shared__ int ssum[1024];
  int t = threadIdx.x;
  int base = t * 16;
  int loc[16];
  int s = 0;
#pragma unroll
  for (int i = 0; i < 16; i++) { loc[i] = s; s += counts[base + i]; }
  ssum[t] = s;
  __syncthreads();
  for (int off = 1; off < 1024; off <<= 1) {
    int v = (t >= off) ? ssum[t - off] : 0;
    __syncthreads();
    ssum[t] += v;
    __syncthreads();
  }
  int excl = (t > 0) ? ssum[t - 1] : 0;
#pragma unroll
  for (int i = 0; i < 16; i++) {
    int o = excl + loc[i];
    offsets[base + i] = o;
    cursor[base + i]  = o;
  }
  if (t == 1023) offsets[NNODE] = excl + s;
}

__global__ void scatter_kernel(const int* __restrict__ src, const int* __restrict__ dst,
                               int* __restrict__ cursor, int* __restrict__ csr_src) {
  int e = blockIdx.x * 256 + threadIdx.x;
  int p = atomicAdd(&cursor[dst[e]], 1);
  csr_src[p] = src[e];
}

// ---------------- MFMA GEMM: out[NN,Nw] = [X(256)|box(7)|1|pad] @ Wt^T ----------------
// 128x128 tile, 4 waves (2x2 of 64x64), K = 9 steps of 32. Single-term bf16.
// Staging: pure global_load_lds (16B). LDS linear [row][64B] (conflict-free).
__global__ __launch_bounds__(256) void gemm_mfma(
    const unsigned short* __restrict__ Ah,
    const unsigned short* __restrict__ bxh,
    const unsigned short* __restrict__ Wth,
    float* __restrict__ out, int Nw, int half_out) {
  __shared__ alignas(16) char lds[2 * 8192];   // A | B, 128 rows x 64B each
  const int tid  = threadIdx.x;
  const int lane = tid & 63;
  const int wave = tid >> 6;
  const int wm = wave >> 1, wn = wave & 1;
  const int m0 = blockIdx.x * 128;
  const int n0 = blockIdx.y * 128;
  const int srow = tid >> 2;
  const int sc8  = (tid & 3) * 8;

  f32x4 acc[4][4];
#pragma unroll
  for (int i = 0; i < 4; i++)
#pragma unroll
    for (int j = 0; j < 4; j++) acc[i][j] = (f32x4)0.0f;

  const int kblk = lane >> 4;
  for (int kt = 0; kt < 9; kt++) {
    if (kt) __syncthreads();
#pragma unroll
    for (int p = 0; p < 2; p++) {
      int row = p * 64 + srow;
      const unsigned short* ga =
          (kt < 8) ? Ah + (size_t)(m0 + row) * 256 + kt * 32 + sc8
                   : bxh + (size_t)(m0 + row) * 32 + sc8;
      gload16(ga, lds + p * 4096 + tid * 16);
      gload16(Wth + (size_t)(n0 + row) * 288 + kt * 32 + sc8,
              lds + 8192 + p * 4096 + tid * 16);
    }
    __syncthreads();   // drains vmcnt (incl. global_load_lds) before ds_read

    bf16x8 ah[4];
#pragma unroll
    for (int i = 0; i < 4; i++) {
      int fm = wm * 64 + i * 16 + (lane & 15);
      ah[i] = *(const bf16x8*)(lds + fm * 64 + 16 * kblk);
    }
#pragma unroll
    for (int j = 0; j < 4; j++) {
      int fn = wn * 64 + j * 16 + (lane & 15);
      bf16x8 bh = *(const bf16x8*)(lds + 8192 + fn * 64 + 16 * kblk);
#pragma unroll
      for (int i = 0; i < 4; i++)
        acc[i][j] = __builtin_amdgcn_mfma_f32_16x16x32_bf16(bh, ah[i], acc[i][j], 0, 0, 0);
    }
  }
#pragma unroll
  for (int i = 0; i < 4; i++) {
    int m = m0 + wm * 64 + i * 16 + (lane & 15);
#pragma unroll
    for (int j = 0; j < 4; j++) {
      int n = n0 + wn * 64 + j * 16 + (lane >> 4) * 4;
      if (half_out) {
        h16x4 o;
        o[0] = to_h16_sat(acc[i][j].x); o[1] = to_h16_sat(acc[i][j].y);
        o[2] = to_h16_sat(acc[i][j].z); o[3] = to_h16_sat(acc[i][j].w);
        *(h16x4*)((_Float16*)out + (size_t)m * Nw + n) = o;
      } else {
        *(f32x4*)(out + (size_t)m * Nw + n) = acc[i][j];
      }
    }
  }
}

// ---------------- node-level stat terms: Σ indeg·Q ; Σ outdeg·P² + indeg·Q² ----------------
// (P's linear term comes from edge_pass's ΣS — do NOT add it here.)
__global__ void dense_terms(const _Float16* __restrict__ PQ,
                            const int* __restrict__ indeg, const int* __restrict__ outdeg,
                            float* __restrict__ psum, float* __restrict__ psq) {
  int c  = threadIdx.x;
  int n0 = blockIdx.x * 8;
  float s = 0.f, s2 = 0.f;
  for (int n = n0; n < n0 + 8; n++) {
    float oc = (float)outdeg[n], ic = (float)indeg[n];
    float p = (float)PQ[(size_t)n * 512 + c];
    float q = (float)PQ[(size_t)n * 512 + 256 + c];
    s  += ic * q;                       // linear P term lives in edge_pass ΣS
    s2 += oc * p * p + ic * q * q;
  }
  atomicAdd(&psum[c], s);
  atomicAdd(&psq[c], s2);
}

// ---------------- edge pass v8b: max(P) + S only; two-bank pipelined gathers ----------------
constexpr int EPB = 8;   // nodes per block (8 waves x 1)
__global__ __launch_bounds__(512) void edge_pass(
    const _Float16* __restrict__ PQ,   // [NN][512] fp16 (P 0:256, Q 256:512)
    const int* __restrict__ offsets, const int* __restrict__ csr_src,
    float* __restrict__ M, float* __restrict__ psum, float* __restrict__ psq) {
  __shared__ float red[2][8][256];
  const int tid = threadIdx.x;
  const int wave = tid >> 6, lane = tid & 63;
  const int h = lane >> 5, li = lane & 31;
  const int c8 = li * 8;
  float S[8] = {};
  float cs[8] = {}, cq[8] = {};

  const int d = blockIdx.x * EPB + wave;
  const int beg = offsets[d], end = offsets[d + 1];

  if (beg < end) {
    h16x8 qv = *(const h16x8*)(PQ + (size_t)d * 512 + 256 + c8);
    h16x2 mx2[4];
    _Float16 NINF = (_Float16)(-INFINITY);
#pragma unroll
    for (int jj = 0; jj < 4; jj++) { mx2[jj][0] = NINF; mx2[jj][1] = NINF; }

#define LOADIDX(I, E)                                                     \
    _Pragma("unroll") for (int i = 0; i < 4; i++) {                       \
      int ei = (E) + 2 * i + h;                                           \
      I[i] = csr_src[ei < end ? ei : end - 1];  /* clamped dup */         \
    }
#define GATHER(P, I)                                                      \
    _Pragma("unroll") for (int i = 0; i < 4; i++)                         \
      P[i] = *(const h16x8*)(PQ + (size_t)I[i] * 512 + c8);
#define PROC(P, E)                                                        \
    {                                                                     \
      const int nl = end - (E);                                           \
      if (nl >= 8) {                                                      \
        _Pragma("unroll") for (int i = 0; i < 4; i++) {                   \
          _Pragma("unroll") for (int jj = 0; jj < 4; jj++) {              \
            h16x2 pp; pp[0] = P[i][2 * jj]; pp[1] = P[i][2 * jj + 1];     \
            mx2[jj] = __builtin_elementwise_max(mx2[jj], pp);             \
          }                                                               \
          _Pragma("unroll") for (int j = 0; j < 8; j++)                   \
            S[j] += (float)P[i][j];                                       \
        }                                                                 \
      } else {                                                            \
        _Pragma("unroll") for (int i = 0; i < 4; i++) {                   \
          const bool live = (2 * i + h) < nl;                             \
          _Pragma("unroll") for (int jj = 0; jj < 4; jj++) {              \
            h16x2 pp; pp[0] = P[i][2 * jj]; pp[1] = P[i][2 * jj + 1];     \
            mx2[jj] = __builtin_elementwise_max(mx2[jj], pp);             \
          }                                                               \
          _Pragma("unroll") for (int j = 0; j < 8; j++)                   \
            S[j] += live ? (float)P[i][j] : 0.f;                          \
        }                                                                 \
      }                                                                   \
    }

    int iA[4], iB[4];
    h16x8 pA[4], pB[4];
    LOADIDX(iA, beg);
    GATHER(pA, iA);
    if (beg + 8 < end) { LOADIDX(iB, beg + 8); GATHER(pB, iB); }
    int e = beg;
    while (true) {
      PROC(pA, e);
      if (e + 16 < end) { LOADIDX(iA, e + 16); GATHER(pA, iA); }
      e += 8;
      if (e >= end) break;
      PROC(pB, e);
      if (e + 16 < end) { LOADIDX(iB, e + 16); GATHER(pB, iB); }
      e += 8;
      if (e >= end) break;
    }
#undef LOADIDX
#undef GATHER
#undef PROC

    float mxf[8], q8[8];
#pragma unroll
    for (int jj = 0; jj < 4; jj++) {
      mxf[2 * jj]     = (float)mx2[jj][0];
      mxf[2 * jj + 1] = (float)mx2[jj][1];
    }
#pragma unroll
    for (int j = 0; j < 8; j++) {
      q8[j] = (float)qv[j];
      mxf[j] = fmaxf(mxf[j], __shfl_xor(mxf[j], 32));
      S[j]  += __shfl_xor(S[j], 32);
    }
    float4 o = (h == 0)
      ? make_float4(mxf[0] + q8[0], mxf[1] + q8[1], mxf[2] + q8[2], mxf[3] + q8[3])
      : make_float4(mxf[4] + q8[4], mxf[5] + q8[5], mxf[6] + q8[6], mxf[7] + q8[7]);
    *(float4*)(M + (size_t)d * 256 + c8 + h * 4) = o;
#pragma unroll
    for (int j = 0; j < 8; j++) {
      cs[j] = S[j];
      cq[j] = 2.0f * q8[j] * S[j];
    }
  }

  // per-wave LDS slot (h==0 lanes hold folded full values), then one atomic/col
  if (h == 0) {
    *(float4*)&red[0][wave][c8]     = make_float4(cs[0], cs[1], cs[2], cs[3]);
    *(float4*)&red[0][wave][c8 + 4] = make_float4(cs[4], cs[5], cs[6], cs[7]);
    *(float4*)&red[1][wave][c8]     = make_float4(cq[0], cq[1], cq[2], cq[3]);
    *(float4*)&red[1][wave][c8 + 4] = make_float4(cq[4], cq[5], cq[6], cq[7]);
  }
  __syncthreads();
  if (tid < 256) {
    float ts = 0.f, tq = 0.f;
#pragma unroll
    for (int w = 0; w < 8; w++) { ts += red[0][w][tid]; tq += red[1][w][tid]; }
    atomicAdd(&psum[tid], ts);
    atomicAdd(&psq[tid], tq);
  }
}

// ---------------- BN stats over dense rows (for x0) ----------------
__global__ void stats_dense(const float* __restrict__ H,
                            float* __restrict__ psum, float* __restrict__ psq) {
  int c  = threadIdx.x;
  int r0 = blockIdx.x * 16;
  float sum = 0.f, sq = 0.f;
  for (int r = r0; r < r0 + 16; r++) {
    float h = H[r * CD + c];
    sum += h;
    sq  += h * h;
  }
  atomicAdd(&psum[c], sum);
  atomicAdd(&psq[c], sq);
}

// normalize + ReLU with FUSED finalize (mu/rstd recomputed per block from
// psum/psq); writes out column block AND (optionally) bf16 copy for the
// next layer's GEMM A-staging.
__global__ void normalize_write(const float* __restrict__ H, const int* __restrict__ counts,
                                const float* __restrict__ psum, const float* __restrict__ psq,
                                float invcount,
                                const float* __restrict__ gamma, const float* __restrict__ beta,
                                float* __restrict__ out, int col0,
                                unsigned short* __restrict__ xh) {
  int c  = threadIdx.x;
  int n0 = blockIdx.x * 8;
  float m = psum[c] * invcount;
  float v = fmaxf(psq[c] * invcount - m * m, 0.0f);
  float rc = (1.0f / sqrtf(v + EPSB)) * gamma[c];
  float bc = beta[c];
  for (int n = n0; n < n0 + 8; n++) {
    float val = 0.0f;
    if (!counts || counts[n] != 0) {
      val = fmaxf((H[n * CD + c] - m) * rc + bc, 0.0f);
    }
    out[n * 1024 + col0 + c] = val;
    if (xh) xh[(size_t)n * 256 + c] = bf_hi_rne(val);
  }
}

// ---------------- launch ----------------
extern "C" void kernel_launch(void* const* d_in, const int* in_sizes, int n_in,
                              void* d_out, int out_size, void* d_ws, size_t ws_size,
                              hipStream_t stream) {
  const float* pf    = (const float*)d_in[0];
  const float* rois  = (const float*)d_in[1];
  const int*   esrc  = (const int*)d_in[2];
  const int*   edst  = (const int*)d_in[3];
  const float* Wg    = (const float*)d_in[4];
  const float* bg    = (const float*)d_in[5];
  const float* gg    = (const float*)d_in[6];
  const float* betag = (const float*)d_in[7];
  const float* Wl[3]  = {(const float*)d_in[8],  (const float*)d_in[12], (const float*)d_in[16]};
  const float* bl[3]  = {(const float*)d_in[9],  (const float*)d_in[13], (const float*)d_in[17]};
  const float* gl[3]  = {(const float*)d_in[10], (const float*)d_in[14], (const float*)d_in[18]};
  const float* bel[3] = {(const float*)d_in[11], (const float*)d_in[15], (const float*)d_in[19]};
  float* out = (float*)d_out;

  // workspace layout (~45 MB)
  float* ws    = (float*)d_ws;
  _Float16* PQ = (_Float16*)ws;                       // NN*512 fp16 = 16 MB
  float* Mbuf  = ws + (size_t)NNODE * 256;            // NN*256 f32 = 16 MB
  unsigned short* Ah  = (unsigned short*)(Mbuf + (size_t)NNODE * CD);  // NN*256 bf16
  unsigned short* bxh = Ah + (size_t)NNODE * 256;     // NN*32
  unsigned short* wt  = bxh + (size_t)NNODE * 32;     // 3 layers x [512*288]
  unsigned short* wtg = wt + 3 * 512 * 288;           // [256*288]
  int* counts  = (int*)(wtg + 256 * 288);             // NN (indeg)   \ zeroed by
  int* outdeg  = counts + NNODE;                      // NN           | single
  float* stats = (float*)(outdeg + NNODE);            // 4 slots x 512| memset
  int* offsets = (int*)(stats + 4 * 512);             // NN+1
  int* cursor  = offsets + NNODE + 1;
  int* csr     = cursor + NNODE;

  // one memset covers counts + outdeg + all 4 stat slots
  hipMemsetAsync(counts, 0, 2 * NNODE * sizeof(int) + 4 * 512 * sizeof(float), stream);
  build_boxf16<<<NNODE / 256, 256, 0, stream>>>(rois, bxh);
  convert_split<<<NNODE * CD / (256 * 8), 256, 0, stream>>>(pf, Ah);
  build_wtg<<<256, 320, 0, stream>>>(Wg, bg, wtg);
  for (int l = 0; l < 3; l++)
    build_wt<<<512, 320, 0, stream>>>(Wl[l], bl[l], wt + l * 512 * 288, l == 0 ? 1 : 0);
  hist_kernel<<<NEDGE / 256, 256, 0, stream>>>(edst, counts);
  hist_kernel<<<NEDGE / 256, 256, 0, stream>>>(esrc, outdeg);
  scan_kernel<<<1, 1024, 0, stream>>>(counts, offsets, cursor);
  scatter_kernel<<<NEDGE / 256, 256, 0, stream>>>(esrc, edst, cursor, csr);

  // x0 = BN-ReLU([pf|box|1] @ Wg+bg)  (fp32 out; Ah refilled with x0 after)
  {
    dim3 g(NNODE / 128, 2);
    gemm_mfma<<<g, 256, 0, stream>>>(Ah, bxh, wtg, Mbuf, 256, 0);
  }
  stats_dense<<<NNODE / 16, 256, 0, stream>>>(Mbuf, stats, stats + 256);
  normalize_write<<<NNODE / 8, 256, 0, stream>>>(Mbuf, nullptr, stats, stats + 256,
                                                 1.0f / NNODE, gg, betag, out, 0, Ah);

  // three EdgeConv layers
  for (int l = 0; l < 3; l++) {
    float* ps = stats + (l + 1) * 512;
    float* pq = ps + 256;
    dim3 g(NNODE / 128, 4);
    gemm_mfma<<<g, 256, 0, stream>>>(Ah, bxh, wt + l * 512 * 288, (float*)PQ, 512, 1);
    dense_terms<<<NNODE / 8, 256, 0, stream>>>(PQ, counts, outdeg, ps, pq);
    edge_pass<<<NNODE / EPB, 512, 0, stream>>>(PQ, offsets, csr, Mbuf, ps, pq);
    normalize_write<<<NNODE / 8, 256, 0, stream>>>(Mbuf, counts, ps, pq,
                                                   1.0f / NEDGE, gl[l], bel[l],
                                                   out, (l + 1) * CD,
                                                   l < 2 ? Ah : nullptr);
  }
}